// Round 2
// baseline (601.561 us; speedup 1.0000x reference)
//
#include <hip/hip_runtime.h>

// UpsamplingNearestSingle: N=262144 coarse voxels, C=64 ch, SCALE=2 -> 8 children.
// d_out (float32, concatenated): fine_data [N*8,64] then fine_ijk [N*8,3] as floats.
#define N_COARSE 262144
#define CHANNELS 64
#define DATA_F4     (N_COARSE * 8 * 16)   // 33554432 output float4s (fine_data)
#define DATA_BLOCKS 131072                // DATA_F4 / 256
#define IJK_ELEMS   (N_COARSE * 8 * 3)    // 6291456
#define IJK_BLOCKS  24576                 // IJK_ELEMS / 256

typedef float nfloat4 __attribute__((ext_vector_type(4)));

// OUTPUT-DRIVEN replication, PLAIN (cached) stores.
// R0 (input-driven, NT) and R1 (output-driven, NT) both measured ~238 us for the
// kernel portion (~2.6 TB/s) despite opposite read/store patterns, while the
// harness fillBuffer sustains 6.25 TB/s on the same destination with plain
// stores. Hypothesis under test: the `nt` store flag caps the write stream at
// ~2.6 TB/s regardless of pattern; plain stores take the cached path the fill
// kernel proves can hit the ceiling.
__global__ void __launch_bounds__(256)
upsample_fused_kernel(const nfloat4* __restrict__ in, const int* __restrict__ ijk,
                      nfloat4* __restrict__ out_data, float* __restrict__ out_ijk) {
    const int b = blockIdx.x;
    if (b < DATA_BLOCKS) {
        const size_t j   = (size_t)b * 256 + threadIdx.x;   // output float4 index
        const size_t src = ((j >> 7) << 4) | (j & 15);      // parent*16 + c4
        out_data[j] = in[src];
    } else {
        const int e = (b - DATA_BLOCKS) * 256 + threadIdx.x;  // [0, IJK_ELEMS)
        const int r = e / 3;           // fine row (magic-mul)
        const int d = e - r * 3;       // dim 0..2
        const int n = r >> 3;          // parent voxel
        const int o = r & 7;           // child index
        const int off = (o >> (2 - d)) & 1;  // meshgrid ij-order offset bit
        out_ijk[e] = (float)(ijk[n * 3 + d] * 2 + off);
    }
}

extern "C" void kernel_launch(void* const* d_in, const int* in_sizes, int n_in,
                              void* d_out, int out_size, void* d_ws, size_t ws_size,
                              hipStream_t stream) {
    const nfloat4* coarse_data = (const nfloat4*)d_in[0];
    const int*     coarse_ijk  = (const int*)d_in[1];

    float*   out      = (float*)d_out;
    nfloat4* out_data = (nfloat4*)out;
    float*   out_ijk  = out + (size_t)N_COARSE * 8 * CHANNELS;  // +134217728

    upsample_fused_kernel<<<DATA_BLOCKS + IJK_BLOCKS, 256, 0, stream>>>(
        coarse_data, coarse_ijk, out_data, out_ijk);
}